// Round 13
// baseline (343.208 us; speedup 1.0000x reference)
//
#include <hip/hip_runtime.h>

typedef int      iv4 __attribute__((ext_vector_type(4)));
typedef unsigned uv4 __attribute__((ext_vector_type(4)));

// ====== v13: v7 producer (nt wse) + 4-way interleaved consume (nt wse) ======
#define BLK1    512
#define EPT1    16
#define CHUNK1  (BLK1 * EPT1)     // 8192 edges per pass-1 chunk
#define CPB     16                // chunks per consume block (= waves in pass 2)
#define BLK2    1024
#define CAP     38400             // LDS segment-accumulator capacity (floats)
#define NREGS   128               // x regions (256 KB each at n_x = 2^23)
#define RSH     16                // region shift: ptr >> 16

// ---- Pass 1: sort each 8192-edge chunk by region, write contiguously ----
__global__ __launch_bounds__(BLK1) void sort_chunks_kernel(
    const float* __restrict__ x,     // only for the (rare) sentinel path
    const int*   __restrict__ ptrs,
    const int*   __restrict__ csr,
    float*       __restrict__ out,
    unsigned*    __restrict__ wse,   // [n_edges] packed entries, chunk-contiguous
    int*         __restrict__ wsb,   // [n_chunks * (NREGS+1)] per-chunk bounds
    long long eb)                    // edges per consume block = CPB*CHUNK1
{
    __shared__ int      hist[NREGS];      // counts -> scatter cursors
    __shared__ int      bounds[NREGS + 1];
    __shared__ unsigned packed[CHUNK1];   // 32 KB

    const int c = blockIdx.x, tid = threadIdx.x;
    const long long base = (long long)c * CHUNK1;
    const int cb = (int)(base / eb);                  // owning consume block
    const int seg_base = csr[(long long)cb * eb];

    if (tid < NREGS) hist[tid] = 0;
    __syncthreads();

    // coalesced index loads (nt: single-use stream)
    int ps[EPT1], cs[EPT1];
    const iv4* p4 = reinterpret_cast<const iv4*>(ptrs + base);
    const iv4* s4 = reinterpret_cast<const iv4*>(csr + base);
    #pragma unroll
    for (int q = 0; q < EPT1 / 4; ++q) {
        iv4 p = __builtin_nontemporal_load(p4 + q * BLK1 + tid);
        ps[q*4+0] = p[0]; ps[q*4+1] = p[1]; ps[q*4+2] = p[2]; ps[q*4+3] = p[3];
    }
    #pragma unroll
    for (int q = 0; q < EPT1 / 4; ++q) {
        iv4 s = __builtin_nontemporal_load(s4 + q * BLK1 + tid);
        cs[q*4+0] = s[0]; cs[q*4+1] = s[1]; cs[q*4+2] = s[2]; cs[q*4+3] = s[3];
    }

    // histogram
    #pragma unroll
    for (int i = 0; i < EPT1; ++i) atomicAdd(&hist[ps[i] >> RSH], 1);
    __syncthreads();
    if (tid == 0) {
        int acc = 0;
        #pragma unroll
        for (int r = 0; r < NREGS; ++r) { bounds[r] = acc; acc += hist[r]; }
        bounds[NREGS] = acc;                           // == CHUNK1
    }
    __syncthreads();
    if (tid < NREGS) hist[tid] = bounds[tid];          // cursors
    __syncthreads();

    // rank + scatter into LDS (unstable ranking fine: consumer accumulates
    // order-independently via LDS atomics)
    #pragma unroll
    for (int i = 0; i < EPT1; ++i) {
        int pp = ps[i], ss = cs[i];
        int r  = pp >> RSH;
        int sl = ss - seg_base;
        unsigned pk;
        if (sl >= 0xFFFF) {                            // pathological: direct add
            atomicAdd(out + ss, x[pp]);
            pk = (((unsigned)pp & 0xFFFFu) << 16) | 0xFFFFu;   // NOP sentinel
        } else {
            pk = (((unsigned)pp & 0xFFFFu) << 16) | (unsigned)sl;
        }
        int pos = atomicAdd(&hist[r], 1);
        packed[pos] = pk;
    }
    __syncthreads();

    // contiguous coalesced write-out (nt: wse is a stream; keep L2 for x)
    {
        const uv4* pl = reinterpret_cast<const uv4*>(packed);
        uv4* w4 = reinterpret_cast<uv4*>(wse + base);
        for (int i = tid; i < CHUNK1 / 4; i += BLK1)
            __builtin_nontemporal_store(pl[i], w4 + i);
    }
    for (int i = tid; i <= NREGS; i += BLK1)
        wsb[(size_t)c * (NREGS + 1) + i] = bounds[i];
}

// ---- Pass 2: region sweep, 4-way interleaved cursors, nt wse stream ----
__global__ __launch_bounds__(BLK2) void consume4_kernel(
    const float*    __restrict__ x,
    const int*      __restrict__ csr,
    float*          __restrict__ out,
    const unsigned* __restrict__ wse,
    const int*      __restrict__ wsb,
    long long eb)
{
    __shared__ float accum[CAP];                 // 150 KB
    __shared__ int   cbnd[CPB][NREGS + 1];       // 8.1 KB

    const int c = blockIdx.x, tid = threadIdx.x;
    const int w = tid >> 6, lane = tid & 63;
    const long long base = (long long)c * eb;

    for (int i = tid; i < CAP; i += BLK2) accum[i] = 0.f;
    {
        const int* src = wsb + (size_t)c * CPB * (NREGS + 1);
        for (int i = tid; i < CPB * (NREGS + 1); i += BLK2)
            (&cbnd[0][0])[i] = src[i];
    }
    const int seg_base = csr[base];
    const int seg_last = csr[base + eb - 1];
    __syncthreads();

    // wave w owns chunk w. Regions in groups of 4 with interleaved cursors:
    // 4 independent pk->x chains per lane (MLP), locality window 4 x 256 KB.
    // wse read with NT so the read-once stream does not evict x from L2.
    const unsigned* wsec = wse + base + (long long)w * CHUNK1;
    for (int g = 0; g < NREGS; g += 4) {
        const int b0 = cbnd[w][g],     b1 = cbnd[w][g + 1];
        const int b2 = cbnd[w][g + 2], b3 = cbnd[w][g + 3];
        const int b4 = cbnd[w][g + 4];
        int i0 = b0 + lane, i1 = b1 + lane, i2 = b2 + lane, i3 = b3 + lane;
        const int rb0 = (g + 0) << RSH, rb1 = (g + 1) << RSH;
        const int rb2 = (g + 2) << RSH, rb3 = (g + 3) << RSH;
        while (i0 < b1 || i1 < b2 || i2 < b3 || i3 < b4) {
            const bool d0 = i0 < b1, d1 = i1 < b2, d2 = i2 < b3, d3 = i3 < b4;
            unsigned p0 = 0, p1 = 0, p2 = 0, p3 = 0;
            if (d0) p0 = __builtin_nontemporal_load(wsec + i0);
            if (d1) p1 = __builtin_nontemporal_load(wsec + i1);
            if (d2) p2 = __builtin_nontemporal_load(wsec + i2);
            if (d3) p3 = __builtin_nontemporal_load(wsec + i3);
            float v0 = 0.f, v1 = 0.f, v2 = 0.f, v3 = 0.f;
            if (d0) v0 = x[rb0 | (int)(p0 >> 16)];
            if (d1) v1 = x[rb1 | (int)(p1 >> 16)];
            if (d2) v2 = x[rb2 | (int)(p2 >> 16)];
            if (d3) v3 = x[rb3 | (int)(p3 >> 16)];
            if (d0) {
                int sl = (int)(p0 & 0xFFFFu);
                if (sl != 0xFFFF) {
                    if (sl < CAP) atomicAdd(&accum[sl], v0);
                    else          atomicAdd(out + seg_base + sl, v0);
                }
            }
            if (d1) {
                int sl = (int)(p1 & 0xFFFFu);
                if (sl != 0xFFFF) {
                    if (sl < CAP) atomicAdd(&accum[sl], v1);
                    else          atomicAdd(out + seg_base + sl, v1);
                }
            }
            if (d2) {
                int sl = (int)(p2 & 0xFFFFu);
                if (sl != 0xFFFF) {
                    if (sl < CAP) atomicAdd(&accum[sl], v2);
                    else          atomicAdd(out + seg_base + sl, v2);
                }
            }
            if (d3) {
                int sl = (int)(p3 & 0xFFFFu);
                if (sl != 0xFFFF) {
                    if (sl < CAP) atomicAdd(&accum[sl], v3);
                    else          atomicAdd(out + seg_base + sl, v3);
                }
            }
            i0 += 64; i1 += 64; i2 += 64; i3 += 64;
        }
    }
    __syncthreads();

    // Flush: interior segments exclusive (csr sorted) -> plain coalesced
    // stores; the two block-boundary segments may be shared -> atomicAdd.
    const int range = seg_last - seg_base + 1;
    const int hi = range < CAP ? range : CAP;
    for (int i = tid; i < hi; i += BLK2) {
        float v = accum[i];
        if (i == 0 || i == range - 1) {
            if (v != 0.f) atomicAdd(out + seg_base + i, v);
        } else {
            out[seg_base + i] = v;
        }
    }
}

// =================== round-5 fallback (generic sizes) ===================
#define EPT   16
#define BLK   256
#define CHUNK (BLK * EPT)
#define NREG  16
#define SW5(s) ((s) ^ (((s) >> 4) & 0xF))

__global__ __launch_bounds__(BLK, 4) void seg_gather_sort_kernel(
    const float* __restrict__ x,
    const int*   __restrict__ ptrs,
    const int*   __restrict__ csr,
    float*       __restrict__ out,
    int n_edges, int rshift, int n_chunks)
{
    __shared__ int      hist[NREG];
    __shared__ int      bounds[NREG + 1];
    __shared__ unsigned packed[CHUNK];
    __shared__ float    vlds[CHUNK];

    const int tid = threadIdx.x;
    const unsigned lmask = (1u << rshift) - 1u;

    for (int c = blockIdx.x; c < n_chunks; c += gridDim.x) {
        const long long base_e = (long long)c * CHUNK;
        if (base_e + CHUNK <= n_edges) {
            const long long e0 = base_e + (long long)tid * EPT;
            const iv4* p4 = reinterpret_cast<const iv4*>(ptrs + e0);
            const iv4* c4 = reinterpret_cast<const iv4*>(csr + e0);
            int ps[EPT], cs[EPT];
            #pragma unroll
            for (int q = 0; q < EPT / 4; ++q) {
                iv4 p = __builtin_nontemporal_load(p4 + q);
                ps[q*4+0] = p[0]; ps[q*4+1] = p[1]; ps[q*4+2] = p[2]; ps[q*4+3] = p[3];
            }
            #pragma unroll
            for (int q = 0; q < EPT / 4; ++q) {
                iv4 cc = __builtin_nontemporal_load(c4 + q);
                cs[q*4+0] = cc[0]; cs[q*4+1] = cc[1]; cs[q*4+2] = cc[2]; cs[q*4+3] = cc[3];
            }
            if (tid < NREG) hist[tid] = 0;
            __syncthreads();
            #pragma unroll
            for (int i = 0; i < EPT; ++i) atomicAdd(&hist[ps[i] >> rshift], 1);
            __syncthreads();
            if (tid == 0) {
                int acc = 0; bounds[0] = 0;
                #pragma unroll
                for (int r = 0; r < NREG; ++r) { acc += hist[r]; bounds[r+1] = acc; }
                #pragma unroll
                for (int r = 0; r < NREG; ++r) hist[r] = bounds[r];
            }
            __syncthreads();
            #pragma unroll
            for (int i = 0; i < EPT; ++i) {
                int r   = ps[i] >> rshift;
                int pos = atomicAdd(&hist[r], 1);
                packed[pos] = (((unsigned)ps[i] & lmask) << 12) | (unsigned)(tid*EPT+i);
            }
            __syncthreads();
            {
                int r = 0;
                #pragma unroll
                for (int k = 0; k < EPT; ++k) {
                    int e = k * BLK + tid;
                    while (e >= bounds[r + 1]) ++r;
                    unsigned pk = packed[e];
                    int ptr  = (r << rshift) | (int)(pk >> 12);
                    int slot = (int)(pk & 0xFFFu);
                    vlds[SW5(slot)] = x[ptr];
                }
            }
            __syncthreads();
            float v[EPT];
            #pragma unroll
            for (int i = 0; i < EPT; ++i) v[i] = vlds[SW5(tid * EPT + i)];
            int cur = cs[0]; float sum = 0.f; bool first = true;
            #pragma unroll
            for (int i = 0; i < EPT; ++i) {
                int seg = cs[i];
                if (seg != cur) {
                    if (first) { atomicAdd(out + cur, sum); first = false; }
                    else       { out[cur] = sum; }
                    cur = seg; sum = 0.f;
                }
                sum += v[i];
            }
            atomicAdd(out + cur, sum);
            __syncthreads();
        } else {
            long long e0 = base_e + (long long)tid * EPT;
            if (e0 < n_edges) {
                long long eend = e0 + EPT; if (eend > n_edges) eend = n_edges;
                int cur = csr[e0]; float sum = 0.f; bool first = true;
                for (long long e = e0; e < eend; ++e) {
                    int seg = csr[e];
                    if (seg != cur) {
                        if (first) { atomicAdd(out + cur, sum); first = false; }
                        else       { out[cur] = sum; }
                        cur = seg; sum = 0.f;
                    }
                    sum += x[ptrs[e]];
                }
                atomicAdd(out + cur, sum);
            }
        }
    }
}

extern "C" void kernel_launch(void* const* d_in, const int* in_sizes, int n_in,
                              void* d_out, int out_size, void* d_ws, size_t ws_size,
                              hipStream_t stream) {
    const float* x    = (const float*)d_in[0];
    const int*   ptrs = (const int*)d_in[1];
    const int*   csr  = (const int*)d_in[2];
    float*       out  = (float*)d_out;

    const int n_x     = in_sizes[0];
    const int n_edges = in_sizes[2];

    // Zero base for atomics + empty segments (d_out poisoned by harness).
    (void)hipMemsetAsync(out, 0, (size_t)out_size * sizeof(float), stream);

    const long long eb = (long long)CHUNK1 * CPB;     // 131072
    const int n_chunks1 = n_edges / CHUNK1;
    const size_t ws_need = (size_t)n_edges * 4 +
                           (size_t)n_chunks1 * (NREGS + 1) * 4;
    const bool v13_ok = (n_edges % eb == 0) &&
                        (n_x <= (NREGS << RSH)) &&
                        (ws_size >= ws_need);

    if (v13_ok) {
        unsigned* wse = (unsigned*)d_ws;
        int*      wsb = (int*)d_ws + n_edges;
        const int g2  = (int)(n_edges / eb);          // 256 consume blocks
        sort_chunks_kernel<<<n_chunks1, BLK1, 0, stream>>>(
            x, ptrs, csr, out, wse, wsb, eb);
        consume4_kernel<<<g2, BLK2, 0, stream>>>(
            x, csr, out, wse, wsb, eb);
    } else {
        int rshift = 0;
        while ((1LL << rshift) < (n_x + NREG - 1) / NREG) ++rshift;
        const int n_chunks = (int)(((long long)n_edges + CHUNK - 1) / CHUNK);
        int grid = 1024; if (grid > n_chunks) grid = n_chunks;
        seg_gather_sort_kernel<<<grid, BLK, 0, stream>>>(
            x, ptrs, csr, out, n_edges, rshift, n_chunks);
    }
}